// Round 1
// baseline (435.959 us; speedup 1.0000x reference)
//
#include <hip/hip_runtime.h>
#include <hip/hip_bf16.h>

#define BB 64
#define TT 1024
#define DD 512
#define NS 24

#define POT_OFF   65536
#define LENS_OFF  1638400
#define TRANS_OFF 1638464

// ---------------------------------------------------------------------------
// Kernel 1: pot = x @ W + b, plus boundary adds; writes pot region of d_out.
// Also writes lens (block 0) and trans copy (block 1).
// Grid: 512 blocks x 128 threads. Each thread owns one row (b*T + t) of pot.
// ---------------------------------------------------------------------------
__global__ __launch_bounds__(128) void gemm_pot(
    const float* __restrict__ x, const float* __restrict__ W,
    const float* __restrict__ bias, const float* __restrict__ trans,
    const float* __restrict__ lb, const float* __restrict__ rb,
    float* __restrict__ out)
{
  __shared__ float xs[128 * 36];   // 128 rows x 32 K-chunk, stride 36 (16B-aligned, conflict-clean)
  const int tid = threadIdx.x;
  const int row0 = blockIdx.x * 128;
  const int row = row0 + tid;
  const int t = row & (TT - 1);

  float acc[NS];
#pragma unroll
  for (int nn = 0; nn < NS; ++nn) acc[nn] = bias[nn];
  if (t == 0) {
#pragma unroll
    for (int nn = 0; nn < NS; ++nn) acc[nn] += lb[nn];
  }
  if (t == TT - 1) {
#pragma unroll
    for (int nn = 0; nn < NS; ++nn) acc[nn] += rb[nn];
  }

  const float* xr = x + (size_t)row0 * DD;

  for (int k0 = 0; k0 < DD; k0 += 32) {
    __syncthreads();
#pragma unroll
    for (int i = 0; i < 8; ++i) {
      int f = tid + i * 128;          // float4 index in [0,1024)
      int r = f >> 3, c = f & 7;
      float4 v = *(const float4*)(xr + (size_t)r * DD + k0 + c * 4);
      *(float4*)(&xs[r * 36 + c * 4]) = v;
    }
    __syncthreads();
#pragma unroll
    for (int kk = 0; kk < 32; kk += 4) {
      float4 xv = *(const float4*)(&xs[tid * 36 + kk]);
      float xj[4] = {xv.x, xv.y, xv.z, xv.w};
#pragma unroll
      for (int j = 0; j < 4; ++j) {
        const int k = k0 + kk + j;
        const float xvj = xj[j];
#pragma unroll
        for (int nn = 0; nn < NS; ++nn)
          acc[nn] = fmaf(xvj, W[k * NS + nn], acc[nn]);   // W addr wave-uniform -> s_load
      }
    }
  }

  float* po = out + POT_OFF + (size_t)row * NS;
#pragma unroll
  for (int i = 0; i < 6; ++i) {
    float4 v = make_float4(acc[4*i], acc[4*i+1], acc[4*i+2], acc[4*i+3]);
    *(float4*)(po + i * 4) = v;
  }

  if (blockIdx.x == 0 && tid < BB) out[LENS_OFF + tid] = (float)TT;
  if (blockIdx.x == 1) {
    for (int i = tid; i < NS * NS; i += 128) out[TRANS_OFF + i] = trans[i];
  }
}

// ---------------------------------------------------------------------------
// Kernel 2: Viterbi forward scan. One wave per batch; alpha wave-uniform in
// SGPRs via v_readlane. Stores all alphas (no argmax here -> reconstructed
// in parallel later). Grid: 64 x 64.
// ---------------------------------------------------------------------------
__global__ __launch_bounds__(64) void viterbi_scan(
    const float* __restrict__ pot, const float* __restrict__ trans,
    float* __restrict__ alphas)
{
  const int b = blockIdx.x;
  const int l = threadIdx.x;
  const int n = l % NS;               // lanes >=24 duplicate (same addr, same value stores: safe)

  float tc[NS];
#pragma unroll
  for (int m = 0; m < NS; ++m) tc[m] = trans[m * NS + n];

  const float* pb = pot + (size_t)b * TT * NS;
  float* ab = alphas + (size_t)b * TT * NS;

  float a0 = pb[n];
  ab[n] = a0;
  float as[NS];
#pragma unroll
  for (int m = 0; m < NS; ++m)
    as[m] = __int_as_float(__builtin_amdgcn_readlane(__float_as_int(a0), m));

  float pv[4];
#pragma unroll
  for (int u = 0; u < 4; ++u) pv[u] = pb[(size_t)(1 + u) * NS + n];

  auto step = [&](int tt, float potv) {
    float sc[NS];
#pragma unroll
    for (int m = 0; m < NS; ++m) sc[m] = as[m] + tc[m];
    float r0 = fmaxf(fmaxf(sc[0],  sc[1]),  sc[2]);
    float r1 = fmaxf(fmaxf(sc[3],  sc[4]),  sc[5]);
    float r2 = fmaxf(fmaxf(sc[6],  sc[7]),  sc[8]);
    float r3 = fmaxf(fmaxf(sc[9],  sc[10]), sc[11]);
    float r4 = fmaxf(fmaxf(sc[12], sc[13]), sc[14]);
    float r5 = fmaxf(fmaxf(sc[15], sc[16]), sc[17]);
    float r6 = fmaxf(fmaxf(sc[18], sc[19]), sc[20]);
    float r7 = fmaxf(fmaxf(sc[21], sc[22]), sc[23]);
    float q0 = fmaxf(fmaxf(r0, r1), r2);
    float q1 = fmaxf(fmaxf(r3, r4), r5);
    float q2 = fmaxf(r6, r7);
    float best = fmaxf(fmaxf(q0, q1), q2);
    float anew = best + potv;
    ab[(size_t)tt * NS + n] = anew;
#pragma unroll
    for (int m = 0; m < NS; ++m)
      as[m] = __int_as_float(__builtin_amdgcn_readlane(__float_as_int(anew), m));
  };

  for (int t = 1; t <= 1017; t += 4) {
#pragma unroll
    for (int u = 0; u < 4; ++u) {
      const int tt = t + u;
      const float potv = pv[u];
      pv[u] = pb[(size_t)(tt + 4) * NS + n];   // prefetch 4 ahead (over-read lands in d_out, unused)
      step(tt, potv);
    }
  }
  step(1021, pv[0]);
  step(1022, pv[1]);
  step(1023, pv[2]);
}

// ---------------------------------------------------------------------------
// Kernel 3: reconstruct backpointers in parallel (bit-exact vs forward):
// bp[b][t][n] = first argmax_m( alpha[b][t-1][m] + trans[m][n] ), t in [1,T)
// ---------------------------------------------------------------------------
__global__ __launch_bounds__(256) void bp_build(
    const float* __restrict__ alphas, const float* __restrict__ trans,
    unsigned char* __restrict__ bp)
{
  const long total = (long)BB * (TT - 1) * NS;
  long idx = (long)blockIdx.x * 256 + threadIdx.x;
  if (idx >= total) return;
  const int nn = (int)(idx % NS);
  const long r = idx / NS;
  const int tm1 = (int)(r % (TT - 1));
  const int b = (int)(r / (TT - 1));
  const int t = tm1 + 1;

  const float* ar = alphas + ((size_t)b * TT + (t - 1)) * NS;
  float best = ar[0] + trans[0 * NS + nn];
  int bi = 0;
#pragma unroll
  for (int m = 1; m < NS; ++m) {
    float s = ar[m] + trans[m * NS + nn];
    bool g = s > best;                // strict > : first-max semantics (jnp.argmax)
    bi = g ? m : bi;
    best = g ? s : best;
  }
  bp[((size_t)b * TT + t) * NS + nn] = (unsigned char)bi;
}

// ---------------------------------------------------------------------------
// Kernel 4: backtrace via chunked function composition (C=32, 32 chunks).
// One block per batch: stage bp in LDS, parallel chunk tables, serial chunk
// boundary walk (32 steps), parallel emit. Writes decoded as float.
// ---------------------------------------------------------------------------
__global__ __launch_bounds__(768) void backtrace(
    const unsigned char* __restrict__ bp, const float* __restrict__ alphas,
    float* __restrict__ out_dec)
{
  __shared__ unsigned char bl[TT * NS];   // 24576 B
  __shared__ int H[32][NS];
  __shared__ int e[32];

  const int b = blockIdx.x, tid = threadIdx.x;

  const uint4* src = (const uint4*)(bp + (size_t)b * TT * NS);
  uint4* dst = (uint4*)bl;
  for (int i = tid; i < (TT * NS) / 16; i += 768) dst[i] = src[i];
  __syncthreads();

  // C1: per-chunk composition tables
  {
    const int c = tid / NS, s = tid % NS;    // c in [0,32)
    int a = s;
    int tlo = c * 32; if (tlo < 1) tlo = 1;
    for (int t = c * 32 + 31; t >= tlo; --t) a = bl[t * NS + a];
    H[c][s] = a;
  }
  __syncthreads();

  // C2: last_tag + chunk-boundary tags (serial, 1 thread)
  if (tid == 0) {
    const float* ar = alphas + ((size_t)b * TT + (TT - 1)) * NS;
    float best = ar[0]; int bi = 0;
#pragma unroll
    for (int nn = 1; nn < NS; ++nn) {
      float v = ar[nn];
      if (v > best) { best = v; bi = nn; }
    }
    int tag = bi;
    e[31] = tag;
    for (int c = 31; c >= 1; --c) { tag = H[c][tag]; e[c - 1] = tag; }
  }
  __syncthreads();

  // C3: emit tags per chunk
  if (tid < 32) {
    const int c = tid;
    int tag = e[c];
    float* od = out_dec + (size_t)b * TT;
    od[c * 32 + 31] = (float)tag;
    for (int t = c * 32 + 30; t >= c * 32; --t) {
      tag = bl[(t + 1) * NS + tag];
      od[t] = (float)tag;
    }
  }
}

// ---------------------------------------------------------------------------
extern "C" void kernel_launch(void* const* d_in, const int* in_sizes, int n_in,
                              void* d_out, int out_size, void* d_ws, size_t ws_size,
                              hipStream_t stream)
{
  const float* x     = (const float*)d_in[0];
  const float* W     = (const float*)d_in[1];
  const float* bias  = (const float*)d_in[2];
  const float* trans = (const float*)d_in[3];
  const float* lb    = (const float*)d_in[4];
  const float* rb    = (const float*)d_in[5];
  float* out = (float*)d_out;

  float* alphas = (float*)d_ws;                                   // 64*1024*24*4 = 6 MB
  unsigned char* bp = (unsigned char*)d_ws + (size_t)BB * TT * NS * 4;  // 1.5 MB

  gemm_pot<<<512, 128, 0, stream>>>(x, W, bias, trans, lb, rb, out);
  viterbi_scan<<<BB, 64, 0, stream>>>(out + POT_OFF, trans, alphas);
  const long total = (long)BB * (TT - 1) * NS;
  bp_build<<<(int)((total + 255) / 256), 256, 0, stream>>>(alphas, trans, bp);
  backtrace<<<BB, 768, 0, stream>>>(bp, alphas, out);
}